// Round 9
// baseline (2739.767 us; speedup 1.0000x reference)
//
#include <hip/hip_runtime.h>

#define BB 64
#define TT 1024
#define DD 512
#define BT (BB*TT)

// partial-exchange mailbox (round-7 proven): parity x b x q(4) x cidx(3) x
// j(128) u32 slots = 768 KiB. Sentinel 0xFFFFFFFF (NaN pattern, unreachable).
#define TAUG_SLOTS (2ULL * 64 * 4 * 3 * 128)
#define SENT32 0xFFFFFFFFu

typedef float f4 __attribute__((ext_vector_type(4)));

// ===========================================================================
// GEMM: C[bt, e'] = sum_d x[bt,d] * W[e',d] + bias[e']   (all f32)
// (unchanged — verified absmax 0.0)
// ===========================================================================
__global__ __launch_bounds__(256, 2) void gemm_kernel(
    const float* __restrict__ x, const float* __restrict__ tau_w,
    const float* __restrict__ tau_b, const float* __restrict__ mem_w,
    const float* __restrict__ mem_b, float* __restrict__ xp, float* __restrict__ mm)
{
    __shared__ float As[32][132];
    __shared__ float Bs[32][68];

    const int tid  = threadIdx.x;
    const int bt0  = blockIdx.x * 128;
    const bool isxp = (blockIdx.y < 8);
    const float* W       = isxp ? tau_w : mem_w;
    const int    wstride = isxp ? 1024 : 512;
    const int    e0      = isxp ? blockIdx.y * 64 : blockIdx.y * 64 - 512;
    const float* bias    = isxp ? tau_b : mem_b;
    float*       dst     = isxp ? xp : mm;

    const int tm = tid & 31, tn = tid >> 5;
    const int lr = tid >> 3, lc = tid & 7;

    float bias_r[8];
#pragma unroll
    for (int ni = 0; ni < 8; ni++) bias_r[ni] = bias[e0 + tn * 8 + ni];

    float acc[4][8] = {};
    float4 pa[4], pb[2];

#pragma unroll
    for (int j = 0; j < 4; j++)
        pa[j] = *(const float4*)(x + (size_t)(bt0 + lr + 32 * j) * DD + lc * 4);
#pragma unroll
    for (int j = 0; j < 2; j++)
        pb[j] = *(const float4*)(W + (size_t)(e0 + lr + 32 * j) * wstride + lc * 4);

    for (int kb = 0; kb < DD; kb += 32) {
#pragma unroll
        for (int j = 0; j < 4; j++) {
            As[lc * 4 + 0][lr + 32 * j] = pa[j].x;
            As[lc * 4 + 1][lr + 32 * j] = pa[j].y;
            As[lc * 4 + 2][lr + 32 * j] = pa[j].z;
            As[lc * 4 + 3][lr + 32 * j] = pa[j].w;
        }
#pragma unroll
        for (int j = 0; j < 2; j++) {
            Bs[lc * 4 + 0][lr + 32 * j] = pb[j].x;
            Bs[lc * 4 + 1][lr + 32 * j] = pb[j].y;
            Bs[lc * 4 + 2][lr + 32 * j] = pb[j].z;
            Bs[lc * 4 + 3][lr + 32 * j] = pb[j].w;
        }
        __syncthreads();
        if (kb + 32 < DD) {
#pragma unroll
            for (int j = 0; j < 4; j++)
                pa[j] = *(const float4*)(x + (size_t)(bt0 + lr + 32 * j) * DD + kb + 32 + lc * 4);
#pragma unroll
            for (int j = 0; j < 2; j++)
                pb[j] = *(const float4*)(W + (size_t)(e0 + lr + 32 * j) * wstride + kb + 32 + lc * 4);
        }
#pragma unroll
        for (int k = 0; k < 32; k++) {
            float4 av  = *(const float4*)&As[k][tm * 4];
            float4 bv0 = *(const float4*)&Bs[k][tn * 8];
            float4 bv1 = *(const float4*)&Bs[k][tn * 8 + 4];
            float a_[4] = {av.x, av.y, av.z, av.w};
            float b_[8] = {bv0.x, bv0.y, bv0.z, bv0.w, bv1.x, bv1.y, bv1.z, bv1.w};
#pragma unroll
            for (int mi = 0; mi < 4; mi++)
#pragma unroll
                for (int ni = 0; ni < 8; ni++)
                    acc[mi][ni] = fmaf(a_[mi], b_[ni], acc[mi][ni]);
        }
        __syncthreads();
    }

#pragma unroll
    for (int mi = 0; mi < 4; mi++) {
        const int row = bt0 + tm * 4 + mi;
        float o[8];
#pragma unroll
        for (int ni = 0; ni < 8; ni++) o[ni] = __fadd_rn(acc[mi][ni], bias_r[ni]);
        float4 s0 = {o[0], o[1], o[2], o[3]};
        float4 s1 = {o[4], o[5], o[6], o[7]};
        *(float4*)(dst + (size_t)row * DD + e0 + tn * 8)     = s0;
        *(float4*)(dst + (size_t)row * DD + e0 + tn * 8 + 4) = s1;
    }
}

// ===========================================================================
// Scan v5 — round-7 protocol (PROVEN, absmax 0.0) + OWNER-TAIL OFFLOAD.
//
// Round-8 lesson: scan blocks are 212+ unified regs/wave -> 2 waves/SIMD ->
// ONE block/CU, zero co-residency slack; single-kernel fusion with GEMM
// occupancy-deadlocks. Reverted. This round shortens the owner's serial
// chain instead (protocol untouched):
//   owner/step:  poll 3 -> sum3 -> sigmoid -> tau publish  [setprio(1)]
//   helper/step: (quarter (p+1)&3, was idle) reads tau(i) from tau_buf one
//     step later, computes alpha/v/spike for step i-1 with IDENTICAL
//     instructions (bitwise-same output), holds v in its regs, prefetches m
//     itself one step early, writes spikes. Spike-store drain and ~120cy of
//     exp/div/blend leave the cross-WG critical path.
// Pre-committed read: delta <= +-3%  => per-step cost is pure MALL
// publish->detect latency; declare practical floor.
// ===========================================================================
__global__ __launch_bounds__(512, 1) void scan_kernel(
    const float* __restrict__ tau_w,
    float* __restrict__ xp_sp,          // out base: xp in, spikes out
    const float* __restrict__ mm,       // ws: m (B,T,D)
    const float* __restrict__ thrp,
    float* __restrict__ tau_out, float* __restrict__ v_out,
    unsigned int* __restrict__ taug32)  // ws: sentinel-filled mailbox
{
    __shared__ __align__(16) float tau_buf[2][128];

    const int bid = blockIdx.x;
    const int b = bid & 63, p = bid >> 6;    // XCD colocation remap
    const int t = threadIdx.x;               // == global weight row e
    const int q = t >> 7;                    // e-quarter of this row
    const int j = t & 127;
    const bool owner  = (q == p);            // waves 2p, 2p+1
    const bool helper = (q == ((p + 1) & 3)); // v/spike offload waves

    // resident weights: Wt[e=t][p*128 .. p*128+127] as 128 scalars
    float wv[128];
    {
        const float4* wrow = (const float4*)(tau_w + (size_t)t * 1024 + 512 + p * 128);
#pragma unroll
        for (int jj = 0; jj < 32; jj++) {
            float4 w4 = wrow[jj];
            wv[4 * jj + 0] = w4.x; wv[4 * jj + 1] = w4.y;
            wv[4 * jj + 2] = w4.z; wv[4 * jj + 3] = w4.w;
        }
    }
#pragma unroll
    for (int jj = 0; jj < 128; jj++) asm volatile("" : "+v"(wv[jj]));  // keep live

    if (t < 128) tau_buf[0][t] = 1.0f;       // tau0 carry = 1.0 (chunk p)

    const float thr = thrp[0];
    float tau_keep = 1.0f;
    float hv = 0.0f, m_hold = 0.0f;          // helper-resident v state
    const size_t baseio = (size_t)b * TT * DD + t;            // owner row
    const size_t baseH  = (size_t)b * TT * DD + p * 128 + j;  // helped row

    __syncthreads();

    for (int i = 0; i < TT; i++) {
        // prefetches (in flight during the dot)
        float xpv = 0.0f, m_next = 0.0f;
        if (owner)  xpv    = xp_sp[baseio + (size_t)i * DD];
        if (helper) m_next = mm   [baseH  + (size_t)i * DD];

        // local dot: chunk-p partial for row e=t (wave-uniform LDS reads)
        float a0 = 0.f, a1 = 0.f, a2 = 0.f, a3 = 0.f;
        {
            const f4* tl = (const f4*)&tau_buf[i & 1][0];
#pragma unroll
            for (int jj = 0; jj < 32; jj++) {
                f4 t4 = tl[jj];
                a0 = fmaf(wv[4 * jj + 0], t4.x, a0);
                a1 = fmaf(wv[4 * jj + 1], t4.y, a1);
                a2 = fmaf(wv[4 * jj + 2], t4.z, a2);
                a3 = fmaf(wv[4 * jj + 3], t4.w, a3);
            }
        }
        const float part = (a0 + a1) + (a2 + a3);   // P_p[e=t], exact tree

        const size_t pb = (size_t)(((i & 1) * 64 + b) * 4);
        if (!owner) {
            // single fire-and-forget publish to e's owner WG
            const int cidx = (p < q) ? p : p - 1;
            __hip_atomic_store(&taug32[(pb + q) * 384 + (size_t)cidx * 128 + j],
                               __float_as_uint(part),
                               __ATOMIC_RELAXED, __HIP_MEMORY_SCOPE_AGENT);
            // helper: v/spike for step i-1 (tau(i) visible since last barrier;
            // m(i-1) held in reg). Instructions identical to the reference.
            if (helper && i > 0) {
                float ta    = tau_buf[i & 1][j];
                float tpe   = __fadd_rn(ta, 1e-6f);
                float alpha = expf(-1.0f / tpe);
                float vn = __fadd_rn(__fmul_rn(alpha, hv),
                                     __fmul_rn(__fsub_rn(1.0f, alpha), m_hold));
                bool s = (vn >= thr);
                xp_sp[baseH + (size_t)(i - 1) * DD] = s ? 1.0f : 0.0f;
                hv = s ? 0.0f : vn;
            }
            if (helper) m_hold = m_next;
        } else {
            __builtin_amdgcn_s_setprio(1);
            // poll the 3 remote partials for row e=t (all kept in flight)
            unsigned int* s0 = &taug32[(pb + p) * 384 + j];
            unsigned int k0, k1, k2;
            do {
                k0 = __hip_atomic_load(s0,       __ATOMIC_RELAXED, __HIP_MEMORY_SCOPE_AGENT);
                k1 = __hip_atomic_load(s0 + 128, __ATOMIC_RELAXED, __HIP_MEMORY_SCOPE_AGENT);
                k2 = __hip_atomic_load(s0 + 256, __ATOMIC_RELAXED, __HIP_MEMORY_SCOPE_AGENT);
            } while (k0 == SENT32 || k1 == SENT32 || k2 == SENT32);
            // re-arm for this slot's next use at step i+2 (drained at barrier)
            __hip_atomic_store(s0,       SENT32, __ATOMIC_RELAXED, __HIP_MEMORY_SCOPE_AGENT);
            __hip_atomic_store(s0 + 128, SENT32, __ATOMIC_RELAXED, __HIP_MEMORY_SCOPE_AGENT);
            __hip_atomic_store(s0 + 256, SENT32, __ATOMIC_RELAXED, __HIP_MEMORY_SCOPE_AGENT);
            const float r0 = __uint_as_float(k0);
            const float r1 = __uint_as_float(k1);
            const float r2 = __uint_as_float(k2);
            // cidx<->chunk: c<p at cidx=c, c>p at cidx=c-1; own chunk = part
            const float pp0 = (p == 0) ? part : r0;
            const float pp1 = (p == 0) ? r0 : ((p == 1) ? part : r1);
            const float pp2 = (p <= 1) ? r1 : ((p == 2) ? part : r2);
            const float pp3 = (p == 3) ? part : r2;

            float dotv  = (pp0 + pp1) + (pp2 + pp3);   // (P0+P1)+(P2+P3) exact
            float z     = __fadd_rn(xpv, dotv);
            float enz   = expf(-z);
            float tau_n = 1.0f / __fadd_rn(1.0f, enz);
            tau_keep = tau_n;
            tau_buf[(i + 1) & 1][j] = tau_n;   // local publish, end of chain
            __builtin_amdgcn_s_setprio(0);
        }
        __syncthreads();   // tau_buf handoff + drains publishes/re-arms
    }

    if (owner) tau_out[b * DD + t] = tau_keep;
    if (helper) {
        // flush step TT-1: tau(TT) = tau_buf[0] (TT even), visible post-barrier
        float ta    = tau_buf[0][j];
        float tpe   = __fadd_rn(ta, 1e-6f);
        float alpha = expf(-1.0f / tpe);
        float vn = __fadd_rn(__fmul_rn(alpha, hv),
                             __fmul_rn(__fsub_rn(1.0f, alpha), m_hold));
        bool s = (vn >= thr);
        xp_sp[baseH + (size_t)(TT - 1) * DD] = s ? 1.0f : 0.0f;
        hv = s ? 0.0f : vn;
        v_out[b * DD + p * 128 + j] = hv;
    }
}

extern "C" void kernel_launch(void* const* d_in, const int* in_sizes, int n_in,
                              void* d_out, int out_size, void* d_ws, size_t ws_size,
                              hipStream_t stream) {
    (void)in_sizes; (void)n_in; (void)out_size; (void)ws_size;
    const float* x     = (const float*)d_in[0];
    const float* tau_w = (const float*)d_in[1];
    const float* tau_b = (const float*)d_in[2];
    const float* mem_w = (const float*)d_in[3];
    const float* mem_b = (const float*)d_in[4];
    const float* thr   = (const float*)d_in[5];
    float* out = (float*)d_out;

    float* mm              = (float*)d_ws;
    unsigned int* taug32   = (unsigned int*)(mm + (size_t)BT * DD);

    // re-arm sentinels (harness poisons d_ws to 0xAA before each replay);
    // 768 KiB — proven workspace footprint.
    hipMemsetAsync(taug32, 0xFF, TAUG_SLOTS * sizeof(unsigned int), stream);

    gemm_kernel<<<dim3(512, 16), 256, 0, stream>>>(x, tau_w, tau_b, mem_w, mem_b,
                                                   out, mm);
    scan_kernel<<<256, 512, 0, stream>>>(tau_w, out, mm, thr,
                                         out + (size_t)BT * DD,
                                         out + (size_t)BT * DD + (size_t)BB * DD,
                                         taug32);
}